// Round 6
// baseline (576.431 us; speedup 1.0000x reference)
//
#include <hip/hip_runtime.h>

// LSTM B=1024,T=512,F=40,H=50 -- MFMA with transposed GEMM + gate-interleaved
// weight rows so the pointwise is THREAD-LOCAL (no gate LDS round trip).
//
// Per block (256 thr = 4 waves, 4 real batches): G^T[200,16] = W'[200,96] @
// [x_t|h]^T[96,16].  A = reordered weights (row' = 4*unit + gate), resident in
// registers (13 M-tiles split 3/3/3/4 across waves, 3 K-chunks each -> 39
// MFMAs/block-step).  B = combined activation rows in LDS ([x(40)|h(50)|pad]),
// double-buffered -> ONE barrier per step.  D gives lane (m=lane&15,q=lane>>4)
// gates i,f,g,o of unit 4*tile+q, batch m, in regs d[0..3]: cell update is
// register-local (c in VGPR), h written straight back as bf16.
// r5 failure mode removed: no D->LDS->gather (was ~2 barriers + ~180 cyc of
// scatter/latency per step on a 2250-cyc serialized step).

constexpr int kT   = 512;
constexpr int kF   = 40;
constexpr int kH   = 50;
constexpr int kMB  = 4;     // real batches per block
constexpr int kRowS = 104;  // combined row stride in shorts (208 B; ~2-way banks)

typedef __attribute__((ext_vector_type(8))) short bf16x8;
typedef __attribute__((ext_vector_type(4))) float f32x4;

__device__ __forceinline__ unsigned short f2bf(float f) {
    union { float f; unsigned u; } v; v.f = f;
    return (unsigned short)((v.u + 0x7FFFu + ((v.u >> 16) & 1u)) >> 16);
}
__device__ __forceinline__ float fast_sigmoid(float v) {
    return __builtin_amdgcn_rcpf(1.f + __expf(-v));
}
__device__ __forceinline__ float fast_tanh(float v) {
    return 1.f - 2.f * __builtin_amdgcn_rcpf(__expf(2.f * v) + 1.f);
}

__global__ __launch_bounds__(256, 1)
void lstm_mfma_tl(
    const float* __restrict__ x,      // [B,T,F]
    const float* __restrict__ W_ih,   // [4H,F]
    const float* __restrict__ W_hh,   // [4H,H]
    const float* __restrict__ b_ih,   // [4H]
    const float* __restrict__ b_hh,   // [4H]
    const float* __restrict__ W1,     // [10,H]
    const float* __restrict__ b1,     // [10]
    const float* __restrict__ W2,     // [1,10]
    const float* __restrict__ b2,     // [1]
    float* __restrict__ out)          // [B]
{
    const int tid  = threadIdx.x;
    const int lane = tid & 63;
    const int wave = tid >> 6;
    const int bb   = blockIdx.x;
    const int m16  = lane & 15;    // B-col / D-col = batch
    const int q    = lane >> 4;    // quad

    __shared__ short sh_comb[2][16][kRowS];  // [x(0..39)|h(40..89)|pad] bf16
    __shared__ float sh_hf[kMB][52];         // final h fp32 for head
    __shared__ float sh_head[kMB][10];

    const int t0 = wave * 3;                 // first tile of this wave
    const int NT = (wave == 3) ? 4 : 3;      // tiles 3/3/3/4 = 13

    // ---- zero both combined buffers (pads + pad batch rows stay 0 forever)
    {
        int* z = (int*)sh_comb;              // 2*16*104*2B = 1664 dwords
        for (int i = tid; i < 1664; i += 256) z[i] = 0;
    }

    // ---- A-frag weights, reordered rows: tile row j' -> unit 4*tile+(j'>>2),
    //      gate j'&3; orig row = unit + 50*gate.  A[m=lane&15][k=q*8+j].
    bf16x8 wa[4][3];
    float  bias[4][4];
    float  cst[4];
    const int uA = m16 >> 2;                 // unit offset within tile (A side)
    const int pA = m16 & 3;                  // gate (A side)
#pragma unroll
    for (int i = 0; i < 4; ++i) {
        const int tl    = t0 + i;
        const int unitA = 4 * tl + uA;
        const int orow  = unitA + 50 * pA;
#pragma unroll
        for (int kk = 0; kk < 3; ++kk) {
            bf16x8 v;
#pragma unroll
            for (int j = 0; j < 8; ++j) {
                const int k = kk * 32 + q * 8 + j;   // combined K index
                float wv = 0.f;
                if (i < NT && unitA < kH) {
                    if (k < kF)            wv = W_ih[orow * kF + k];
                    else if (k < kF + kH)  wv = W_hh[orow * kH + (k - kF)];
                }
                v[j] = (short)f2bf(wv);
            }
            wa[i][kk] = v;
        }
        const int uD = 4 * tl + q;           // D-side unit for this lane
#pragma unroll
        for (int r = 0; r < 4; ++r)
            bias[i][r] = (i < NT && uD < kH)
                       ? (b_ih[uD + 50 * r] + b_hh[uD + 50 * r]) : 0.f;
        cst[i] = (tl == 0 && q == 0) ? 1.f : 0.f;   // c0[:,0] = 1
    }

    // ---- x staging pipeline: thread tid<80 owns (batch m, dword d) = feature
    //      pair (2d,2d+1); 3-deep prefetch (load-to-use ~3 steps).
    const bool  xw = (tid < 80);
    const int   xm = xw ? (tid / 20) : 0;
    const int   xd = xw ? (tid % 20) : 0;
    const float* xrow = x + ((size_t)(bb * kMB + xm) * kT) * kF + 2 * xd;
    float2 wx = {0.f, 0.f}, pf0 = {0.f, 0.f}, pf1 = {0.f, 0.f};

    __syncthreads();                          // zero-init complete
    if (xw) {
        float2 v0 = *(const float2*)(xrow);   // x_0
        unsigned pk = (unsigned)f2bf(v0.x) | ((unsigned)f2bf(v0.y) << 16);
        *(unsigned*)&sh_comb[0][xm][2 * xd] = pk;
        wx  = *(const float2*)(xrow + (size_t)1 * kF);   // x_1
        pf0 = *(const float2*)(xrow + (size_t)2 * kF);   // x_2
        pf1 = *(const float2*)(xrow + (size_t)3 * kF);   // x_3
    }
    __syncthreads();

    // ================= time loop: ONE barrier per step =================
    for (int t = 0; t < kT; ++t) {
        const short* row = &sh_comb[t & 1][m16][0];
        bf16x8 bv0 = *(const bf16x8*)(row +      q * 8);   // k  0..31
        bf16x8 bv1 = *(const bf16x8*)(row + 32 + q * 8);   // k 32..63
        bf16x8 bv2 = *(const bf16x8*)(row + 64 + q * 8);   // k 64..95

        short* nbuf = &sh_comb[(t + 1) & 1][0][0];

#pragma unroll
        for (int i = 0; i < 4; ++i) {
            if (i < NT) {                                  // wave-uniform
                f32x4 d;
                d[0] = bias[i][0]; d[1] = bias[i][1];
                d[2] = bias[i][2]; d[3] = bias[i][3];
                d = __builtin_amdgcn_mfma_f32_16x16x32_bf16(wa[i][0], bv0, d, 0, 0, 0);
                d = __builtin_amdgcn_mfma_f32_16x16x32_bf16(wa[i][1], bv1, d, 0, 0, 0);
                d = __builtin_amdgcn_mfma_f32_16x16x32_bf16(wa[i][2], bv2, d, 0, 0, 0);
                // lane holds gates i,f,g,o of (unit 4*tile+q, batch m16)
                float i_s = fast_sigmoid(d[0]);
                float f_s = fast_sigmoid(d[1]);
                float g_t = fast_tanh   (d[2]);
                float o_s = fast_sigmoid(d[3]);
                float cn  = fmaf(f_s, cst[i], i_s * g_t);
                cst[i] = cn;
                float hv = o_s * fast_tanh(cn);
                const int uD = 4 * (t0 + i) + q;
                if (m16 < kMB && uD < kH) {
                    nbuf[m16 * kRowS + kF + uD] = (short)f2bf(hv);
                    if (t == kT - 1) sh_hf[m16][uD] = hv;
                }
            }
        }

        // stage x_{t+1} into the next buffer; slide the 3-deep pipe
        if (xw) {
            if (t + 1 < kT) {
                unsigned pk = (unsigned)f2bf(wx.x) | ((unsigned)f2bf(wx.y) << 16);
                *(unsigned*)&nbuf[xm * kRowS + 2 * xd] = pk;
            }
            wx = pf0; pf0 = pf1;
            if (t + 4 < kT) pf1 = *(const float2*)(xrow + (size_t)(t + 4) * kF);
        }
        __syncthreads();
    }

    // ---- head: relu(h @ W1.T + b1) @ W2.T + b2 + x[b, T-1, 0] ----
    if (tid < kMB * 10) {
        const int m = tid / 10, j = tid % 10;
        float acc = b1[j];
#pragma unroll
        for (int k = 0; k < kH; ++k) acc = fmaf(sh_hf[m][k], W1[j * kH + k], acc);
        sh_head[m][j] = fmaxf(acc, 0.f);
    }
    __syncthreads();
    if (tid < kMB) {
        float acc = b2[0];
#pragma unroll
        for (int u2 = 0; u2 < 10; ++u2) acc = fmaf(sh_head[tid][u2], W2[u2], acc);
        const int bidx = bb * kMB + tid;
        out[bidx] = acc + x[((size_t)bidx * kT + (kT - 1)) * kF];
    }
}

extern "C" void kernel_launch(void* const* d_in, const int* in_sizes, int n_in,
                              void* d_out, int out_size, void* d_ws, size_t ws_size,
                              hipStream_t stream) {
    const float* x    = (const float*)d_in[0];
    const float* W_ih = (const float*)d_in[1];
    const float* W_hh = (const float*)d_in[2];
    const float* b_ih = (const float*)d_in[3];
    const float* b_hh = (const float*)d_in[4];
    const float* W1   = (const float*)d_in[5];
    const float* b1   = (const float*)d_in[6];
    const float* W2   = (const float*)d_in[7];
    const float* b2   = (const float*)d_in[8];
    float* out = (float*)d_out;

    lstm_mfma_tl<<<dim3(1024 / kMB), dim3(256), 0, stream>>>(
        x, W_ih, W_hh, b_ih, b_hh, W1, b1, W2, b2, out);
}

// Round 7
// 359.311 us; speedup vs baseline: 1.6043x; 1.6043x over previous
//
#include <hip/hip_runtime.h>

// LSTM B=1024,T=512,F=40,H=50. r5/r6 showed the step is LATENCY-bound
// (~2300 cyc chain, pipes <35% busy) with exactly 1 block/CU (grid 256).
// r7: kMB=2, grid=512 -> 2 independent serial chains per CU fill each
// other's stalls. Dense pointwise (100 owner threads, c in register),
// bias folded into MFMA C operand, masked ds_write_b128 D-store (2 real
// cols only), x prefetch distance 2 via 2-phase unroll.
//
// GEMM per step: G^T[208,16] = W'[208,96] @ [x|h]^T[96,16], rows' =
// 4*unit+gate (i,f,g,o interleaved), 13 M-tiles split 3/3/3/4 over 4 waves,
// 3 K-chunks (K=96: x 0..39 | h 40..89 | pad). D lane (m16,q) holds gates
// r=0..3 of unit 4*tile+q, batch col m16 (only m16<2 real).

constexpr int kT   = 512;
constexpr int kF   = 40;
constexpr int kH   = 50;
constexpr int kMB  = 2;      // real batches per block
constexpr int kRowS = 104;   // combined panel row stride in shorts (208 B)
constexpr int kGRow = 208;   // sh_g row stride in dwords (13 tiles * 16)

typedef __attribute__((ext_vector_type(8))) short bf16x8;
typedef __attribute__((ext_vector_type(4))) float f32x4;

__device__ __forceinline__ unsigned short f2bf(float f) {
    union { float f; unsigned u; } v; v.f = f;
    return (unsigned short)((v.u + 0x7FFFu + ((v.u >> 16) & 1u)) >> 16);
}
__device__ __forceinline__ float fast_sigmoid(float v) {
    return __builtin_amdgcn_rcpf(1.f + __expf(-v));
}
__device__ __forceinline__ float fast_tanh(float v) {
    return 1.f - 2.f * __builtin_amdgcn_rcpf(__expf(2.f * v) + 1.f);
}

__global__ __launch_bounds__(256, 2)
void lstm_mfma_2cu(
    const float* __restrict__ x,      // [B,T,F]
    const float* __restrict__ W_ih,   // [4H,F]
    const float* __restrict__ W_hh,   // [4H,H]
    const float* __restrict__ b_ih,   // [4H]
    const float* __restrict__ b_hh,   // [4H]
    const float* __restrict__ W1,     // [10,H]
    const float* __restrict__ b1,     // [10]
    const float* __restrict__ W2,     // [1,10]
    const float* __restrict__ b2,     // [1]
    float* __restrict__ out)          // [B]
{
    const int tid  = threadIdx.x;
    const int lane = tid & 63;
    const int wave = tid >> 6;
    const int bb   = blockIdx.x;
    const int m16  = lane & 15;    // D col = batch
    const int q    = lane >> 4;    // quad

    __shared__ short sh_comb[2][16][kRowS];  // [x(0..39)|h(40..89)|pad] bf16
    __shared__ float sh_g[kMB][kGRow];       // gate pre-acts, rows' = 4u+r
    __shared__ float sh_hf[kMB][kH + 2];     // final h fp32
    __shared__ float sh_head[kMB][10];

    const int t0 = (wave == 3) ? 9 : wave * 3;   // first tile of this wave
    const int NT = (wave == 3) ? 4 : 3;          // tiles 3/3/3/4 = 13

    // zero the combined panels (pads + batch cols 2..15 stay 0 forever)
    { int* z = (int*)sh_comb; for (int i = tid; i < 1664; i += 256) z[i] = 0; }

    // ---- A-frag weights (registers) + bias for C operand ----
    bf16x8 wa[4][3];
    float  bias[4][4];
    const int uA = m16 >> 2, gA = m16 & 3;
#pragma unroll
    for (int i = 0; i < 4; ++i) {
        const int tl = t0 + i;
        const int unitA = 4 * tl + uA;
        const bool live = (i < NT) && (unitA < kH);
        const int orow = live ? (unitA + 50 * gA) : 0;
#pragma unroll
        for (int kk = 0; kk < 3; ++kk) {
            bf16x8 v;
#pragma unroll
            for (int j = 0; j < 8; ++j) {
                const int k = kk * 32 + q * 8 + j;
                float wv = 0.f;
                if (live) {
                    if (k < kF)           wv = W_ih[orow * kF + k];
                    else if (k < kF + kH) wv = W_hh[orow * kH + (k - kF)];
                }
                v[j] = (short)f2bf(wv);
            }
            wa[i][kk] = v;
        }
        const int uD = 4 * tl + q;
#pragma unroll
        for (int r = 0; r < 4; ++r)
            bias[i][r] = (i < NT && uD < kH)
                       ? (b_ih[uD + 50 * r] + b_hh[uD + 50 * r]) : 0.f;
    }

    // ---- dense pointwise owners: tid<100 -> (batch pm, unit pu) ----
    const bool pw = (tid < kMB * kH);
    const int  pm = pw ? (tid / kH) : 0;
    const int  pu = pw ? (tid % kH) : 0;
    float c     = (pw && pu == 0) ? 1.f : 0.f;   // c0[:,0] = 1
    float lasth = 0.f;

    // ---- x stagers: wave 2 lanes 0..39 own (batch xm, float2 chunk xd) ----
    const bool xs = (tid >= 128 && tid < 128 + kMB * 20);
    const int  xi = xs ? (tid - 128) : 0;
    const int  xm = xi / 20, xd = xi % 20;
    const float* xrow = x + ((size_t)(bb * kMB + xm) * kT) * kF + 2 * xd;

    float2 pa = {0.f, 0.f}, pb = {0.f, 0.f};
    __syncthreads();                              // zero-init done
    if (xs) {
        float2 v0 = *(const float2*)xrow;         // x_0
        unsigned pk = (unsigned)f2bf(v0.x) | ((unsigned)f2bf(v0.y) << 16);
        *(unsigned*)&sh_comb[0][xm][2 * xd] = pk;
        pa = *(const float2*)(xrow + (size_t)1 * kF);   // x_1 (used t=0)
        pb = *(const float2*)(xrow + (size_t)2 * kF);   // x_2 (used t=1)
    }
    __syncthreads();

    // ---- one step; CUR = t&1 compile-time via 2-phase unroll ----
    auto step = [&](int t, int CUR, float2& pf) {
        const short* rowp = &sh_comb[CUR][m16][0];
        bf16x8 bv0 = *(const bf16x8*)(rowp +      q * 8);   // k  0..31
        bf16x8 bv1 = *(const bf16x8*)(rowp + 32 + q * 8);   // k 32..63
        bf16x8 bv2 = *(const bf16x8*)(rowp + 64 + q * 8);   // k 64..95
#pragma unroll
        for (int i = 0; i < 4; ++i) {
            if (i < NT) {                                   // wave-uniform
                f32x4 d;
                d[0] = bias[i][0]; d[1] = bias[i][1];
                d[2] = bias[i][2]; d[3] = bias[i][3];
                d = __builtin_amdgcn_mfma_f32_16x16x32_bf16(wa[i][0], bv0, d, 0, 0, 0);
                d = __builtin_amdgcn_mfma_f32_16x16x32_bf16(wa[i][1], bv1, d, 0, 0, 0);
                d = __builtin_amdgcn_mfma_f32_16x16x32_bf16(wa[i][2], bv2, d, 0, 0, 0);
                if (m16 < kMB)                              // 2 real cols only
                    *(f32x4*)&sh_g[m16][16 * (t0 + i) + 4 * q] = d;
            }
        }
        __syncthreads();                                    // A: sh_g ready

        short* nbuf = &sh_comb[CUR ^ 1][0][0];
        if (pw) {
            f32x4 g = *(const f32x4*)&sh_g[pm][4 * pu];     // i,f,g,o of unit pu
            float i_s = fast_sigmoid(g[0]);
            float f_s = fast_sigmoid(g[1]);
            float g_t = fast_tanh   (g[2]);
            float o_s = fast_sigmoid(g[3]);
            c = fmaf(f_s, c, i_s * g_t);
            lasth = o_s * fast_tanh(c);
            if (t + 1 < kT)
                nbuf[pm * kRowS + kF + pu] = (short)f2bf(lasth);
        } else if (xs) {
            if (t + 1 < kT) {
                unsigned pk = (unsigned)f2bf(pf.x) | ((unsigned)f2bf(pf.y) << 16);
                *(unsigned*)&nbuf[xm * kRowS + 2 * xd] = pk;
            }
            if (t + 3 < kT)                                  // distance-2 prefetch
                pf = *(const float2*)(xrow + (size_t)(t + 3) * kF);
        }
        __syncthreads();                                    // B: panel ready
    };

    for (int t = 0; t < kT; t += 2) {
        step(t,     0, pa);
        step(t + 1, 1, pb);
    }

    // ---- head: relu(h @ W1.T + b1) @ W2.T + b2 + x[b, T-1, 0] ----
    if (pw) sh_hf[pm][pu] = lasth;
    __syncthreads();
    if (tid < kMB * 10) {
        const int m = tid / 10, j = tid % 10;
        float acc = b1[j];
#pragma unroll
        for (int k = 0; k < kH; ++k) acc = fmaf(sh_hf[m][k], W1[j * kH + k], acc);
        sh_head[m][j] = fmaxf(acc, 0.f);
    }
    __syncthreads();
    if (tid < kMB) {
        float acc = b2[0];
#pragma unroll
        for (int j2 = 0; j2 < 10; ++j2) acc = fmaf(sh_head[tid][j2], W2[j2], acc);
        const int bidx = bb * kMB + tid;
        out[bidx] = acc + x[((size_t)bidx * kT + (kT - 1)) * kF];
    }
}

extern "C" void kernel_launch(void* const* d_in, const int* in_sizes, int n_in,
                              void* d_out, int out_size, void* d_ws, size_t ws_size,
                              hipStream_t stream) {
    const float* x    = (const float*)d_in[0];
    const float* W_ih = (const float*)d_in[1];
    const float* W_hh = (const float*)d_in[2];
    const float* b_ih = (const float*)d_in[3];
    const float* b_hh = (const float*)d_in[4];
    const float* W1   = (const float*)d_in[5];
    const float* b1   = (const float*)d_in[6];
    const float* W2   = (const float*)d_in[7];
    const float* b2   = (const float*)d_in[8];
    float* out = (float*)d_out;

    lstm_mfma_2cu<<<dim3(1024 / kMB), dim3(256), 0, stream>>>(
        x, W_ih, W_hh, b_ih, b_hh, W1, b1, W2, b2, out);
}